// Round 3
// baseline (1597.088 us; speedup 1.0000x reference)
//
#include <hip/hip_runtime.h>

#define N_READ   200000
#define N_INTRON 50000
#define N_EDGES  2000000

typedef float f4 __attribute__((ext_vector_type(4)));
typedef float f2 __attribute__((ext_vector_type(2)));
typedef int   i4 __attribute__((ext_vector_type(4)));
typedef unsigned short u16x4 __attribute__((ext_vector_type(4)));

// ---------------- degree count + per-edge rank (rank = atomic return, u16) ----------------
__global__ void k_count(const i4* __restrict__ src4, const i4* __restrict__ dst4,
                        int* __restrict__ cnt_r, int* __restrict__ cnt_i,
                        u16x4* __restrict__ rank_r4, u16x4* __restrict__ rank_i4) {
  int i = blockIdx.x * blockDim.x + threadIdx.x;
  if (i >= N_EDGES / 4) return;
  i4 s = src4[i], d = dst4[i];
  u16x4 rr, ri;
  rr.x = (unsigned short)atomicAdd(&cnt_r[s.x], 1);
  rr.y = (unsigned short)atomicAdd(&cnt_r[s.y], 1);
  rr.z = (unsigned short)atomicAdd(&cnt_r[s.z], 1);
  rr.w = (unsigned short)atomicAdd(&cnt_r[s.w], 1);
  ri.x = (unsigned short)atomicAdd(&cnt_i[d.x], 1);
  ri.y = (unsigned short)atomicAdd(&cnt_i[d.y], 1);
  ri.z = (unsigned short)atomicAdd(&cnt_i[d.z], 1);
  ri.w = (unsigned short)atomicAdd(&cnt_i[d.w], 1);
  rank_r4[i] = rr;
  rank_i4[i] = ri;
}

// ---------------- exclusive scan (3 phases) ----------------
__global__ void k_scan1(const int* __restrict__ cnt, int* __restrict__ rp,
                        int* __restrict__ bsum, int n) {
  __shared__ int lds[256];
  int t = threadIdx.x;
  int i = blockIdx.x * 256 + t;
  int v = (i < n) ? cnt[i] : 0;
  lds[t] = v;
  __syncthreads();
  for (int off = 1; off < 256; off <<= 1) {
    int x = (t >= off) ? lds[t - off] : 0;
    __syncthreads();
    lds[t] += x;
    __syncthreads();
  }
  if (i < n) rp[i + 1] = lds[t];
  if (t == 255) bsum[blockIdx.x] = lds[255];
}

__global__ void k_scan2(int* __restrict__ bsum, int nb) {
  __shared__ int lds[1024];
  int t = threadIdx.x;
  int v = (t < nb) ? bsum[t] : 0;
  lds[t] = v;
  __syncthreads();
  for (int off = 1; off < 1024; off <<= 1) {
    int x = (t >= off) ? lds[t - off] : 0;
    __syncthreads();
    lds[t] += x;
    __syncthreads();
  }
  if (t < nb) bsum[t] = lds[t];
}

__global__ void k_scan3(const int* __restrict__ cnt, int* __restrict__ rp,
                        const int* __restrict__ bsum, float* __restrict__ rs, int n) {
  int i = blockIdx.x * 256 + threadIdx.x;
  if (i >= n) return;
  int off = (blockIdx.x == 0) ? 0 : bsum[blockIdx.x - 1];
  rp[i + 1] += off;
  int c = cnt[i];
  rs[i] = rsqrtf((float)(c > 0 ? c : 1));
  if (i == 0) rp[0] = 0;
}

// ---------------- atomic-free CSR fill: slot = rp[node] + rank[edge] ----------------
__global__ void k_fill(const i4* __restrict__ src4, const i4* __restrict__ dst4,
                       const u16x4* __restrict__ rank_r4, const u16x4* __restrict__ rank_i4,
                       const int* __restrict__ rp_r, const int* __restrict__ rp_i,
                       unsigned short* __restrict__ csr_di_r, int* __restrict__ csr_si_i) {
  int i = blockIdx.x * blockDim.x + threadIdx.x;
  if (i >= N_EDGES / 4) return;
  i4 s = src4[i], d = dst4[i];
  u16x4 rr = rank_r4[i], ri = rank_i4[i];
  csr_di_r[rp_r[s.x] + (int)rr.x] = (unsigned short)d.x;
  csr_di_r[rp_r[s.y] + (int)rr.y] = (unsigned short)d.y;
  csr_di_r[rp_r[s.z] + (int)rr.z] = (unsigned short)d.z;
  csr_di_r[rp_r[s.w] + (int)rr.w] = (unsigned short)d.w;
  csr_si_i[rp_i[d.x] + (int)ri.x] = s.x;
  csr_si_i[rp_i[d.y] + (int)ri.y] = s.y;
  csr_si_i[rp_i[d.z] + (int)ri.z] = s.z;
  csr_si_i[rp_i[d.w] + (int)ri.w] = s.w;
}

// ---------------- layer-0 input prep: pad 10->16 and pre-scale by rs_read ----------------
__global__ void k_prep_h0(const float* __restrict__ h_read, const float* __restrict__ rs_r,
                          float* __restrict__ h16) {
  int i = blockIdx.x * blockDim.x + threadIdx.x;
  if (i >= N_READ * 16) return;
  int n = i >> 4, c = i & 15;
  h16[i] = (c < 10) ? h_read[n * 10 + c] * rs_r[n] : 0.0f;
}

__global__ void k_prep_W0(const float* __restrict__ W0, float* __restrict__ W0p) {
  int i = blockIdx.x * blockDim.x + threadIdx.x;
  if (i >= 16 * 64) return;
  int k = i >> 6, j = i & 63;
  W0p[i] = (k < 10) ? W0[k * 64 + j] : 0.0f;
}

// ---------------- fused aggregate + GEMM + epilogue layer ----------------
// CHUNK=true (read-dst layers): column-chunked gather (16 cols/chunk -> 3.2 MB
// per-XCD L2 working set) interleaved with partial register GEMM; eidx is u16.
// CHUNK=false: full-row gather into LDS then GEMM (intron-dst layers).
// FC=true (L5): keep output tile in LDS, apply 128->2 projection in-block.
template <int DIN, int DOUT, bool FC, bool CHUNK, typename ET>
__launch_bounds__(256)
__global__ void k_layer(const float* __restrict__ hsrc, const int* __restrict__ rp,
                        const ET* __restrict__ eidx, const float* __restrict__ rs_dst,
                        const float* __restrict__ W, const float* __restrict__ bias,
                        const float* __restrict__ atts, int li,
                        const float* __restrict__ rs_next,  // may be null
                        float* __restrict__ hout,
                        const float* __restrict__ fcw, const float* __restrict__ fcb,
                        float* __restrict__ fcout, int n_dst) {
  constexpr int NT = 32;
  constexpr int JG = DOUT / 4;
  constexpr int NG = 256 / JG;
  constexpr int NPT = NT / NG;
  const int tid = threadIdx.x;
  const int nbase = blockIdx.x * NT;
  const int jg = tid % JG, ng = tid / JG;
  const int j0 = jg * 4;

  if constexpr (CHUNK) {
    constexpr int SMSZ = FC ? 32 * 132 : 32 * 16;
    __shared__ float smem[SMSZ];
    const int l = tid & 63;
    const int wv = tid >> 6;
    const int node = wv * 8 + (l >> 3);  // 0..31
    const int slot = (l >> 2) & 1;
    const int c4 = l & 3;
    const int n = nbase + node;
    int e0 = 0, e1 = 0;
    float rsd = 0.f;
    if (n < n_dst) { e0 = rp[n]; e1 = rp[n + 1]; rsd = rs_dst[n]; }

    f4 acc[NPT];
#pragma unroll
    for (int p = 0; p < NPT; ++p) acc[p] = (f4){0.f, 0.f, 0.f, 0.f};

    for (int c = 0; c < DIN; c += 16) {
      const int cb = c + c4 * 4;
      f4 a0 = {0.f, 0.f, 0.f, 0.f}, a1 = a0, a2 = a0, a3 = a0;
      int e = e0 + slot;
      for (; e + 6 < e1; e += 8) {
        int s0 = (int)eidx[e], s1 = (int)eidx[e + 2];
        int s2 = (int)eidx[e + 4], s3 = (int)eidx[e + 6];
        a0 += *(const f4*)&hsrc[s0 * DIN + cb];
        a1 += *(const f4*)&hsrc[s1 * DIN + cb];
        a2 += *(const f4*)&hsrc[s2 * DIN + cb];
        a3 += *(const f4*)&hsrc[s3 * DIN + cb];
      }
      for (; e < e1; e += 2) a0 += *(const f4*)&hsrc[(int)eidx[e] * DIN + cb];
      a0 = (a0 + a1) + (a2 + a3);
#pragma unroll
      for (int q = 0; q < 4; ++q) a0[q] += __shfl_xor(a0[q], 4);  // combine 2 edge-slots
      if (slot == 0) *(f4*)&smem[node * 16 + c4 * 4] = a0 * rsd;
      __syncthreads();
      // partial GEMM: acc += rows_c @ W[c:c+16, :]
#pragma unroll
      for (int k = 0; k < 16; k += 4) {
        f4 wr[4];
#pragma unroll
        for (int u = 0; u < 4; ++u) wr[u] = *(const f4*)&W[(c + k + u) * DOUT + j0];
#pragma unroll
        for (int p = 0; p < NPT; ++p) {
          f4 r = *(const f4*)&smem[(ng + p * NG) * 16 + k];
#pragma unroll
          for (int u = 0; u < 4; ++u) acc[p] += r[u] * wr[u];
        }
      }
      __syncthreads();
    }

    const float gate = 1.f / (1.f + __expf(-atts[li]));
    const f4 b4 = *(const f4*)&bias[j0];
    if constexpr (!FC) {
#pragma unroll
      for (int p = 0; p < NPT; ++p) {
        const int nl = ng + p * NG;
        const int n2 = nbase + nl;
        if (n2 < n_dst) {
          f4 v = (acc[p] + b4) * gate;
#pragma unroll
          for (int q = 0; q < 4; ++q) v[q] = fmaxf(v[q], 0.f);
          if (rs_next) v *= rs_next[n2];
          *(f4*)&hout[(size_t)n2 * DOUT + j0] = v;
        }
      }
    } else {
#pragma unroll
      for (int p = 0; p < NPT; ++p) {
        const int nl = ng + p * NG;
        f4 v = (acc[p] + b4) * gate;
#pragma unroll
        for (int q = 0; q < 4; ++q) v[q] = fmaxf(v[q], 0.f);
        *(f4*)&smem[nl * 132 + j0] = v;
      }
      __syncthreads();
      // fc: 256 threads = 32 nodes x 2 cols x 4 partial-sums
      const int nl = tid >> 3, cc = (tid >> 2) & 1, part = tid & 3;
      float s = 0.f;
      const int k0 = part * 32;
#pragma unroll 8
      for (int k = k0; k < k0 + 32; ++k) s += smem[nl * 132 + k] * fcw[k * 2 + cc];
      s += __shfl_xor(s, 1);
      s += __shfl_xor(s, 2);
      const int n2 = nbase + nl;
      if (part == 0 && n2 < n_dst) fcout[n2 * 2 + cc] = s + fcb[cc];
    }
  } else {
    // -------- non-chunked path (intron-dst layers: L0 DIN=16, L2/L4 DIN=128) --------
    constexpr int RSTR = DIN + 4;
    __shared__ float rows[NT * RSTR];
    const int team = tid >> 6, lane = tid & 63;

    if constexpr (DIN == 128) {
      const int sub = lane >> 5, l32 = lane & 31;
      for (int tl = 0; tl < 4; ++tl) {
        const int t = team * 8 + tl * 2 + sub;
        const int n = nbase + t;
        f4 a0 = {0.f, 0.f, 0.f, 0.f}, a1 = a0, a2 = a0, a3 = a0;
        if (n < n_dst) {
          const int e0 = rp[n], e1 = rp[n + 1];
          int e = e0;
          for (; e + 4 <= e1; e += 4) {
            int s0 = (int)eidx[e], s1 = (int)eidx[e + 1];
            int s2 = (int)eidx[e + 2], s3 = (int)eidx[e + 3];
            a0 += *(const f4*)&hsrc[(size_t)s0 * 128 + l32 * 4];
            a1 += *(const f4*)&hsrc[(size_t)s1 * 128 + l32 * 4];
            a2 += *(const f4*)&hsrc[(size_t)s2 * 128 + l32 * 4];
            a3 += *(const f4*)&hsrc[(size_t)s3 * 128 + l32 * 4];
          }
          for (; e < e1; ++e) a0 += *(const f4*)&hsrc[(size_t)(int)eidx[e] * 128 + l32 * 4];
          a0 = (a0 + a1) + (a2 + a3);
          a0 *= rs_dst[n];
        }
        *(f4*)&rows[t * RSTR + l32 * 4] = a0;
      }
    } else {  // DIN == 16
      const int sub = lane >> 3, l8 = lane & 7;
      const int t = team * 8 + sub;
      const int n = nbase + t;
      f2 a0 = {0.f, 0.f}, a1 = a0, a2 = a0, a3 = a0;
      if (n < n_dst) {
        const int e0 = rp[n], e1 = rp[n + 1];
        int e = e0;
        for (; e + 4 <= e1; e += 4) {
          int s0 = (int)eidx[e], s1 = (int)eidx[e + 1];
          int s2 = (int)eidx[e + 2], s3 = (int)eidx[e + 3];
          a0 += *(const f2*)&hsrc[(size_t)s0 * 16 + l8 * 2];
          a1 += *(const f2*)&hsrc[(size_t)s1 * 16 + l8 * 2];
          a2 += *(const f2*)&hsrc[(size_t)s2 * 16 + l8 * 2];
          a3 += *(const f2*)&hsrc[(size_t)s3 * 16 + l8 * 2];
        }
        for (; e < e1; ++e) a0 += *(const f2*)&hsrc[(size_t)(int)eidx[e] * 16 + l8 * 2];
        a0 = (a0 + a1) + (a2 + a3);
        a0 *= rs_dst[n];
      }
      *(f2*)&rows[t * RSTR + l8 * 2] = a0;
    }
    __syncthreads();

    f4 acc[NPT];
#pragma unroll
    for (int p = 0; p < NPT; ++p) acc[p] = (f4){0.f, 0.f, 0.f, 0.f};

#pragma unroll 2
    for (int k = 0; k < DIN; k += 4) {
      f4 w[4];
#pragma unroll
      for (int u = 0; u < 4; ++u) w[u] = *(const f4*)&W[(k + u) * DOUT + j0];
#pragma unroll
      for (int p = 0; p < NPT; ++p) {
        f4 r = *(const f4*)&rows[(ng + p * NG) * RSTR + k];
#pragma unroll
        for (int u = 0; u < 4; ++u) acc[p] += r[u] * w[u];
      }
    }

    const float gate = 1.f / (1.f + __expf(-atts[li]));
    const f4 b4 = *(const f4*)&bias[j0];
#pragma unroll
    for (int p = 0; p < NPT; ++p) {
      const int nl = ng + p * NG;
      const int n = nbase + nl;
      if (n < n_dst) {
        f4 v = (acc[p] + b4) * gate;
#pragma unroll
        for (int q = 0; q < 4; ++q) v[q] = fmaxf(v[q], 0.f);
        if (rs_next) v *= rs_next[n];
        *(f4*)&hout[(size_t)n * DOUT + j0] = v;
      }
    }
  }
}

extern "C" void kernel_launch(void* const* d_in, const int* in_sizes, int n_in,
                              void* d_out, int out_size, void* d_ws, size_t ws_size,
                              hipStream_t stream) {
  const float* h_read = (const float*)d_in[0];
  const int* esrc = (const int*)d_in[1];
  const int* edst = (const int*)d_in[2];
  const float* W0 = (const float*)d_in[3];
  const float* b0 = (const float*)d_in[4];
  const float* W1 = (const float*)d_in[5];
  const float* b1 = (const float*)d_in[6];
  const float* W2 = (const float*)d_in[7];
  const float* b2 = (const float*)d_in[8];
  const float* W3 = (const float*)d_in[9];
  const float* b3 = (const float*)d_in[10];
  const float* W4 = (const float*)d_in[11];
  const float* b4 = (const float*)d_in[12];
  const float* W5 = (const float*)d_in[13];
  const float* b5 = (const float*)d_in[14];
  const float* atts = (const float*)d_in[15];
  const float* fcw = (const float*)d_in[16];
  const float* fcb = (const float*)d_in[17];
  float* out = (float*)d_out;

  char* w = (char*)d_ws;
  size_t off = 0;
  auto alloc = [&](size_t bytes) -> void* {
    void* p = w + off;
    off += (bytes + 15) & ~(size_t)15;  // 16B-align every array
    return p;
  };
  int* cnt_r = (int*)alloc(N_READ * 4);
  int* cnt_i = (int*)alloc(N_INTRON * 4);  // contiguous with cnt_r for one memset
  int* rp_r = (int*)alloc((N_READ + 1) * 4);
  int* rp_i = (int*)alloc((N_INTRON + 1) * 4);
  int* bsum = (int*)alloc(1024 * 4);
  float* rs_r = (float*)alloc(N_READ * 4);
  float* rs_i = (float*)alloc(N_INTRON * 4);
  unsigned short* csr_di_r = (unsigned short*)alloc(N_EDGES * 2);  // intron ids by read
  int* csr_si_i = (int*)alloc(N_EDGES * 4);                        // read ids by intron
  float* W0p = (float*)alloc(16 * 64 * 4);
  float* hR = (float*)alloc((size_t)N_READ * 128 * 4);
  float* hI = (float*)alloc((size_t)N_INTRON * 128 * 4);
  // Time-multiplexed aliases inside hR (dead until L1 writes it):
  //   rank_r/rank_i (u16) live count->fill; h16 lives prep_h0->L0.
  unsigned short* rank_r = (unsigned short*)hR;
  unsigned short* rank_i = rank_r + N_EDGES;
  float* h16 = (float*)hR;

  // --- graph preprocessing (per launch; deterministic work) ---
  hipMemsetAsync(cnt_r, 0, (size_t)(N_READ + N_INTRON) * sizeof(int), stream);
  const int gE4 = (N_EDGES / 4 + 255) / 256;  // 1954
  k_count<<<gE4, 256, 0, stream>>>((const i4*)esrc, (const i4*)edst, cnt_r, cnt_i,
                                   (u16x4*)rank_r, (u16x4*)rank_i);

  const int nbR = (N_READ + 255) / 256;    // 782
  const int nbI = (N_INTRON + 255) / 256;  // 196
  k_scan1<<<nbR, 256, 0, stream>>>(cnt_r, rp_r, bsum, N_READ);
  k_scan2<<<1, 1024, 0, stream>>>(bsum, nbR);
  k_scan3<<<nbR, 256, 0, stream>>>(cnt_r, rp_r, bsum, rs_r, N_READ);
  k_scan1<<<nbI, 256, 0, stream>>>(cnt_i, rp_i, bsum, N_INTRON);
  k_scan2<<<1, 1024, 0, stream>>>(bsum, nbI);
  k_scan3<<<nbI, 256, 0, stream>>>(cnt_i, rp_i, bsum, rs_i, N_INTRON);
  k_fill<<<gE4, 256, 0, stream>>>((const i4*)esrc, (const i4*)edst,
                                  (const u16x4*)rank_r, (const u16x4*)rank_i,
                                  rp_r, rp_i, csr_di_r, csr_si_i);

  k_prep_h0<<<(N_READ * 16 + 255) / 256, 256, 0, stream>>>(h_read, rs_r, h16);
  k_prep_W0<<<4, 256, 0, stream>>>(W0, W0p);

  // --- 6 fused layers ---
  const int gI = (N_INTRON + 31) / 32;  // 1563
  const int gR = (N_READ + 31) / 32;    // 6250
  // L0: read->intron, 16(pad)->64, full-row gather (int eidx)
  k_layer<16, 64, false, false, int><<<gI, 256, 0, stream>>>(
      h16, rp_i, csr_si_i, rs_i, W0p, b0, atts, 0, rs_i, hI, nullptr, nullptr, nullptr, N_INTRON);
  // L1: intron->read, 64->128, chunked gather (u16 eidx)
  k_layer<64, 128, false, true, unsigned short><<<gR, 256, 0, stream>>>(
      hI, rp_r, csr_di_r, rs_r, W1, b1, atts, 1, rs_r, hR, nullptr, nullptr, nullptr, N_READ);
  // L2: read->intron, 128->128, full-row gather
  k_layer<128, 128, false, false, int><<<gI, 256, 0, stream>>>(
      hR, rp_i, csr_si_i, rs_i, W2, b2, atts, 2, rs_i, hI, nullptr, nullptr, nullptr, N_INTRON);
  // L3: intron->read, chunked
  k_layer<128, 128, false, true, unsigned short><<<gR, 256, 0, stream>>>(
      hI, rp_r, csr_di_r, rs_r, W3, b3, atts, 3, rs_r, hR, nullptr, nullptr, nullptr, N_READ);
  // L4: read->intron, full-row gather
  k_layer<128, 128, false, false, int><<<gI, 256, 0, stream>>>(
      hR, rp_i, csr_si_i, rs_i, W4, b4, atts, 4, rs_i, hI, nullptr, nullptr, nullptr, N_INTRON);
  // L5: intron->read, chunked, fc fused in-block
  k_layer<128, 128, true, true, unsigned short><<<gR, 256, 0, stream>>>(
      hI, rp_r, csr_di_r, rs_r, W5, b5, atts, 5, nullptr, hR, fcw, fcb, out, N_READ);
}

// Round 4
// 1136.512 us; speedup vs baseline: 1.4053x; 1.4053x over previous
//
#include <hip/hip_runtime.h>

#define N_READ   200000
#define N_INTRON 50000
#define N_EDGES  2000000

#define NB    256                          // edge-segment blocks for hist/scatter
#define EPB   ((N_EDGES + NB - 1) / NB)    // 7813 edges per block
#define NBUK  782                          // buckets per direction (782*64>=50000, 782*256>=200000)
#define SH_I  6                            // intron bucket shift: 64 introns/bucket
#define SH_R  8                            // read bucket shift: 256 reads/bucket
#define NITEMS (NBUK * NB)                 // 200192 (divisible by 256)

typedef float f4 __attribute__((ext_vector_type(4)));
typedef float f2 __attribute__((ext_vector_type(2)));

// ---------------- bucket histograms (per-block LDS, no global atomics) ----------------
__global__ void kb_hist(const int* __restrict__ src, const int* __restrict__ dst,
                        int* __restrict__ histI, int* __restrict__ histR) {
  __shared__ int hI[1024], hR[1024];
  const int t = threadIdx.x, b = blockIdx.x;
  for (int k = t; k < 1024; k += 256) { hI[k] = 0; hR[k] = 0; }
  __syncthreads();
  const int s0 = b * EPB;
  const int s1 = (s0 + EPB < N_EDGES) ? s0 + EPB : N_EDGES;
  for (int i = s0 + t; i < s1; i += 256) {
    atomicAdd(&hI[dst[i] >> SH_I], 1);
    atomicAdd(&hR[src[i] >> SH_R], 1);
  }
  __syncthreads();
  for (int k = t; k < NBUK; k += 256) {
    histI[k * NB + b] = hI[k];
    histR[k * NB + b] = hR[k];
  }
}

// ---------------- exclusive scan (3 phases, reused) ----------------
__global__ void k_scan1(const int* __restrict__ cnt, int* __restrict__ rp,
                        int* __restrict__ bsum, int n) {
  __shared__ int lds[256];
  int t = threadIdx.x;
  int i = blockIdx.x * 256 + t;
  int v = (i < n) ? cnt[i] : 0;
  lds[t] = v;
  __syncthreads();
  for (int off = 1; off < 256; off <<= 1) {
    int x = (t >= off) ? lds[t - off] : 0;
    __syncthreads();
    lds[t] += x;
    __syncthreads();
  }
  if (i < n) rp[i + 1] = lds[t];
  if (t == 255) bsum[blockIdx.x] = lds[255];
}

__global__ void k_scan2(int* __restrict__ bsum, int nb) {
  __shared__ int lds[1024];
  int t = threadIdx.x;
  int v = (t < nb) ? bsum[t] : 0;
  lds[t] = v;
  __syncthreads();
  for (int off = 1; off < 1024; off <<= 1) {
    int x = (t >= off) ? lds[t - off] : 0;
    __syncthreads();
    lds[t] += x;
    __syncthreads();
  }
  if (t < nb) bsum[t] = lds[t];
}

__global__ void k_scan3b(int* __restrict__ rp, const int* __restrict__ bsum, int n) {
  int i = blockIdx.x * 256 + threadIdx.x;
  if (i >= n) return;
  int off = (blockIdx.x == 0) ? 0 : bsum[blockIdx.x - 1];
  rp[i + 1] += off;
  if (i == 0) rp[0] = 0;
}

// ---------------- scatter edges into buckets (LDS cursors, packed u32 records) ----------------
__global__ void kb_scatter(const int* __restrict__ src, const int* __restrict__ dst,
                           const int* __restrict__ scanI, const int* __restrict__ scanR,
                           unsigned* __restrict__ bI, unsigned* __restrict__ bR) {
  __shared__ int cI[1024], cR[1024];
  const int t = threadIdx.x, b = blockIdx.x;
  for (int k = t; k < NBUK; k += 256) {
    cI[k] = scanI[k * NB + b];
    cR[k] = scanR[k * NB + b];
  }
  __syncthreads();
  const int s0 = b * EPB;
  const int s1 = (s0 + EPB < N_EDGES) ? s0 + EPB : N_EDGES;
  for (int i = s0 + t; i < s1; i += 256) {
    int s = src[i], d = dst[i];
    int slot = atomicAdd(&cI[d >> SH_I], 1);
    bI[slot] = ((unsigned)s << SH_I) | (unsigned)(d & 63);        // 18+6 = 24 bits
    int slot2 = atomicAdd(&cR[s >> SH_R], 1);
    bR[slot2] = ((unsigned)d << SH_R) | (unsigned)(s & 255);      // 16+8 = 24 bits
  }
}

// ---------------- fine CSR per bucket: local hist + LDS scan + scatter ----------------
template <int NBINS, int SH, typename PT>
__global__ void kb_fine(const unsigned* __restrict__ bk, const int* __restrict__ scan,
                        int* __restrict__ rp, float* __restrict__ rs,
                        PT* __restrict__ csr, int n_nodes) {
  __shared__ int hist[NBINS], cur[NBINS], lds[256];
  const int t = threadIdx.x, k = blockIdx.x;
  for (int j = t; j < NBINS; j += 256) hist[j] = 0;
  __syncthreads();
  const int s0 = scan[k * NB];
  const int e0 = (k + 1 < NBUK) ? scan[(k + 1) * NB] : N_EDGES;
  for (int i = s0 + t; i < e0; i += 256) atomicAdd(&hist[bk[i] & (NBINS - 1)], 1);
  __syncthreads();
  // inclusive ladder over 256 slots (NBINS <= 256), then exclusive
  int v = (t < NBINS) ? hist[t] : 0;
  lds[t] = v;
  __syncthreads();
  for (int off = 1; off < 256; off <<= 1) {
    int x = (t >= off) ? lds[t - off] : 0;
    __syncthreads();
    lds[t] += x;
    __syncthreads();
  }
  if (t < NBINS) {
    int base = s0 + lds[t] - hist[t];
    cur[t] = base;
    int n = k * NBINS + t;
    if (n < n_nodes) {
      rp[n] = base;
      rs[n] = rsqrtf((float)(hist[t] > 0 ? hist[t] : 1));
    }
  }
  if (k == NBUK - 1 && t == 0) rp[n_nodes] = N_EDGES;
  __syncthreads();
  for (int i = s0 + t; i < e0; i += 256) {
    unsigned v2 = bk[i];
    int slot = atomicAdd(&cur[v2 & (NBINS - 1)], 1);
    csr[slot] = (PT)(v2 >> SH);
  }
}

// ---------------- layer-0 input prep: pad 10->16 and pre-scale by rs_read ----------------
__global__ void k_prep_h0(const float* __restrict__ h_read, const float* __restrict__ rs_r,
                          float* __restrict__ h16) {
  int i = blockIdx.x * blockDim.x + threadIdx.x;
  if (i >= N_READ * 16) return;
  int n = i >> 4, c = i & 15;
  h16[i] = (c < 10) ? h_read[n * 10 + c] * rs_r[n] : 0.0f;
}

__global__ void k_prep_W0(const float* __restrict__ W0, float* __restrict__ W0p) {
  int i = blockIdx.x * blockDim.x + threadIdx.x;
  if (i >= 16 * 64) return;
  int k = i >> 6, j = i & 63;
  W0p[i] = (k < 10) ? W0[k * 64 + j] : 0.0f;
}

// ---------------- fused aggregate + GEMM + epilogue layer (round-2 structure) ----------------
template <int DIN, int DOUT, bool FC, typename ET>
__launch_bounds__(256)
__global__ void k_layer(const float* __restrict__ hsrc, const int* __restrict__ rp,
                        const ET* __restrict__ eidx, const float* __restrict__ rs_dst,
                        const float* __restrict__ W, const float* __restrict__ bias,
                        const float* __restrict__ atts, int li,
                        const float* __restrict__ rs_next,  // may be null
                        float* __restrict__ hout,
                        const float* __restrict__ fcw, const float* __restrict__ fcb,
                        float* __restrict__ fcout, int n_dst) {
  constexpr int NT = 32;
  constexpr int RSTR = DIN + 4;  // padded LDS row stride (floats)
  __shared__ float rows[NT * RSTR];
  const int tid = threadIdx.x;
  const int nbase = blockIdx.x * NT;
  const int team = tid >> 6, lane = tid & 63;

  if constexpr (DIN == 128) {
    const int sub = lane >> 5, l32 = lane & 31;
    for (int tl = 0; tl < 4; ++tl) {
      const int t = team * 8 + tl * 2 + sub;
      const int n = nbase + t;
      f4 a0 = {0.f, 0.f, 0.f, 0.f}, a1 = a0, a2 = a0, a3 = a0;
      if (n < n_dst) {
        const int e0 = rp[n], e1 = rp[n + 1];
        int e = e0;
        for (; e + 4 <= e1; e += 4) {
          int s0 = (int)eidx[e], s1 = (int)eidx[e + 1];
          int s2 = (int)eidx[e + 2], s3 = (int)eidx[e + 3];
          a0 += *(const f4*)&hsrc[(size_t)s0 * 128 + l32 * 4];
          a1 += *(const f4*)&hsrc[(size_t)s1 * 128 + l32 * 4];
          a2 += *(const f4*)&hsrc[(size_t)s2 * 128 + l32 * 4];
          a3 += *(const f4*)&hsrc[(size_t)s3 * 128 + l32 * 4];
        }
        for (; e < e1; ++e) a0 += *(const f4*)&hsrc[(size_t)(int)eidx[e] * 128 + l32 * 4];
        a0 = (a0 + a1) + (a2 + a3);
        a0 *= rs_dst[n];
      }
      *(f4*)&rows[t * RSTR + l32 * 4] = a0;
    }
  } else if constexpr (DIN == 64) {
    const int sub = lane >> 4, l16 = lane & 15;
    for (int tl = 0; tl < 2; ++tl) {
      const int t = team * 8 + tl * 4 + sub;
      const int n = nbase + t;
      f4 a0 = {0.f, 0.f, 0.f, 0.f}, a1 = a0, a2 = a0, a3 = a0;
      if (n < n_dst) {
        const int e0 = rp[n], e1 = rp[n + 1];
        int e = e0;
        for (; e + 4 <= e1; e += 4) {
          int s0 = (int)eidx[e], s1 = (int)eidx[e + 1];
          int s2 = (int)eidx[e + 2], s3 = (int)eidx[e + 3];
          a0 += *(const f4*)&hsrc[(size_t)s0 * 64 + l16 * 4];
          a1 += *(const f4*)&hsrc[(size_t)s1 * 64 + l16 * 4];
          a2 += *(const f4*)&hsrc[(size_t)s2 * 64 + l16 * 4];
          a3 += *(const f4*)&hsrc[(size_t)s3 * 64 + l16 * 4];
        }
        for (; e < e1; ++e) a0 += *(const f4*)&hsrc[(size_t)(int)eidx[e] * 64 + l16 * 4];
        a0 = (a0 + a1) + (a2 + a3);
        a0 *= rs_dst[n];
      }
      *(f4*)&rows[t * RSTR + l16 * 4] = a0;
    }
  } else {  // DIN == 16
    const int sub = lane >> 3, l8 = lane & 7;
    const int t = team * 8 + sub;
    const int n = nbase + t;
    f2 a0 = {0.f, 0.f}, a1 = a0, a2 = a0, a3 = a0;
    if (n < n_dst) {
      const int e0 = rp[n], e1 = rp[n + 1];
      int e = e0;
      for (; e + 4 <= e1; e += 4) {
        int s0 = (int)eidx[e], s1 = (int)eidx[e + 1];
        int s2 = (int)eidx[e + 2], s3 = (int)eidx[e + 3];
        a0 += *(const f2*)&hsrc[(size_t)s0 * 16 + l8 * 2];
        a1 += *(const f2*)&hsrc[(size_t)s1 * 16 + l8 * 2];
        a2 += *(const f2*)&hsrc[(size_t)s2 * 16 + l8 * 2];
        a3 += *(const f2*)&hsrc[(size_t)s3 * 16 + l8 * 2];
      }
      for (; e < e1; ++e) a0 += *(const f2*)&hsrc[(size_t)(int)eidx[e] * 16 + l8 * 2];
      a0 = (a0 + a1) + (a2 + a3);
      a0 *= rs_dst[n];
    }
    *(f2*)&rows[t * RSTR + l8 * 2] = a0;
  }
  __syncthreads();

  // GEMM: thread computes NPT nodes x 4 cols; nodes interleaved by NG
  constexpr int JG = DOUT / 4;
  constexpr int NG = 256 / JG;
  constexpr int NPT = NT / NG;
  const int jg = tid % JG, ng = tid / JG;
  const int j0 = jg * 4;

  f4 acc[NPT];
#pragma unroll
  for (int p = 0; p < NPT; ++p) acc[p] = (f4){0.f, 0.f, 0.f, 0.f};

#pragma unroll 2
  for (int k = 0; k < DIN; k += 4) {
    f4 w[4];
#pragma unroll
    for (int u = 0; u < 4; ++u) w[u] = *(const f4*)&W[(k + u) * DOUT + j0];
#pragma unroll
    for (int p = 0; p < NPT; ++p) {
      f4 r = *(const f4*)&rows[(ng + p * NG) * RSTR + k];
#pragma unroll
      for (int u = 0; u < 4; ++u) acc[p] += r[u] * w[u];
    }
  }

  const float gate = 1.f / (1.f + __expf(-atts[li]));
  const f4 b4 = *(const f4*)&bias[j0];

  if constexpr (!FC) {
#pragma unroll
    for (int p = 0; p < NPT; ++p) {
      const int nl = ng + p * NG;
      const int n = nbase + nl;
      if (n < n_dst) {
        f4 v = (acc[p] + b4) * gate;
#pragma unroll
        for (int c = 0; c < 4; ++c) v[c] = fmaxf(v[c], 0.f);
        if (rs_next) v *= rs_next[n];
        *(f4*)&hout[(size_t)n * DOUT + j0] = v;
      }
    }
  } else {
    __syncthreads();  // everyone done reading rows before we overwrite it
#pragma unroll
    for (int p = 0; p < NPT; ++p) {
      const int nl = ng + p * NG;
      f4 v = (acc[p] + b4) * gate;
#pragma unroll
      for (int c = 0; c < 4; ++c) v[c] = fmaxf(v[c], 0.f);
      *(f4*)&rows[nl * RSTR + j0] = v;
    }
    __syncthreads();
    // fc: 256 threads = 32 nodes x 2 cols x 4 partial-sums
    const int nl = tid >> 3, c = (tid >> 2) & 1, part = tid & 3;
    float s = 0.f;
    const int k0 = part * 32;
#pragma unroll 8
    for (int k = k0; k < k0 + 32; ++k) s += rows[nl * RSTR + k] * fcw[k * 2 + c];
    s += __shfl_xor(s, 1);
    s += __shfl_xor(s, 2);
    const int n = nbase + nl;
    if (part == 0 && n < n_dst) fcout[n * 2 + c] = s + fcb[c];
  }
}

extern "C" void kernel_launch(void* const* d_in, const int* in_sizes, int n_in,
                              void* d_out, int out_size, void* d_ws, size_t ws_size,
                              hipStream_t stream) {
  const float* h_read = (const float*)d_in[0];
  const int* esrc = (const int*)d_in[1];
  const int* edst = (const int*)d_in[2];
  const float* W0 = (const float*)d_in[3];
  const float* b0 = (const float*)d_in[4];
  const float* W1 = (const float*)d_in[5];
  const float* b1 = (const float*)d_in[6];
  const float* W2 = (const float*)d_in[7];
  const float* b2 = (const float*)d_in[8];
  const float* W3 = (const float*)d_in[9];
  const float* b3 = (const float*)d_in[10];
  const float* W4 = (const float*)d_in[11];
  const float* b4 = (const float*)d_in[12];
  const float* W5 = (const float*)d_in[13];
  const float* b5 = (const float*)d_in[14];
  const float* atts = (const float*)d_in[15];
  const float* fcw = (const float*)d_in[16];
  const float* fcb = (const float*)d_in[17];
  float* out = (float*)d_out;

  char* w = (char*)d_ws;
  size_t off = 0;
  auto alloc = [&](size_t bytes) -> void* {
    void* p = w + off;
    off += (bytes + 15) & ~(size_t)15;  // 16B-align every array
    return p;
  };
  int* rp_r = (int*)alloc((N_READ + 1) * 4);
  int* rp_i = (int*)alloc((N_INTRON + 1) * 4);
  int* bsum = (int*)alloc(1024 * 4);
  float* rs_r = (float*)alloc(N_READ * 4);
  float* rs_i = (float*)alloc(N_INTRON * 4);
  unsigned short* csr_di_r = (unsigned short*)alloc(N_EDGES * 2);  // intron ids by read
  int* csr_si_i = (int*)alloc(N_EDGES * 4);                        // read ids by intron
  float* W0p = (float*)alloc(16 * 64 * 4);
  int* histI = (int*)alloc(NITEMS * 4);
  int* scanI = (int*)alloc((NITEMS + 1) * 4);
  int* histR = (int*)alloc(NITEMS * 4);
  int* scanR = (int*)alloc((NITEMS + 1) * 4);
  float* hR = (float*)alloc((size_t)N_READ * 128 * 4);
  float* hI = (float*)alloc((size_t)N_INTRON * 128 * 4);
  // Time-multiplexed aliases inside hR (dead until L1 writes it):
  //   h16 lives prep_h0 -> L0 at hR+0 (12.8 MB);
  //   bucketed edge records live kb_scatter -> kb_fine at hR+16MB (2x8 MB).
  float* h16 = hR;
  unsigned* bI = (unsigned*)((char*)hR + (size_t)16 * 1024 * 1024);
  unsigned* bR = bI + N_EDGES;

  // --- CSR build: bucket histogram -> scan -> scatter -> per-bucket fine CSR ---
  kb_hist<<<NB, 256, 0, stream>>>(esrc, edst, histI, histR);
  k_scan1<<<NITEMS / 256, 256, 0, stream>>>(histI, scanI, bsum, NITEMS);
  k_scan2<<<1, 1024, 0, stream>>>(bsum, NITEMS / 256);
  k_scan3b<<<NITEMS / 256, 256, 0, stream>>>(scanI, bsum, NITEMS);
  k_scan1<<<NITEMS / 256, 256, 0, stream>>>(histR, scanR, bsum, NITEMS);
  k_scan2<<<1, 1024, 0, stream>>>(bsum, NITEMS / 256);
  k_scan3b<<<NITEMS / 256, 256, 0, stream>>>(scanR, bsum, NITEMS);
  kb_scatter<<<NB, 256, 0, stream>>>(esrc, edst, scanI, scanR, bI, bR);
  kb_fine<64, SH_I, int><<<NBUK, 256, 0, stream>>>(bI, scanI, rp_i, rs_i, csr_si_i, N_INTRON);
  kb_fine<256, SH_R, unsigned short><<<NBUK, 256, 0, stream>>>(bR, scanR, rp_r, rs_r, csr_di_r, N_READ);

  k_prep_h0<<<(N_READ * 16 + 255) / 256, 256, 0, stream>>>(h_read, rs_r, h16);
  k_prep_W0<<<4, 256, 0, stream>>>(W0, W0p);

  // --- 6 fused layers ---
  const int gI = (N_INTRON + 31) / 32;  // 1563
  const int gR = (N_READ + 31) / 32;    // 6250
  // L0: read->intron, 16(pad)->64 (int eidx)
  k_layer<16, 64, false, int><<<gI, 256, 0, stream>>>(
      h16, rp_i, csr_si_i, rs_i, W0p, b0, atts, 0, rs_i, hI, nullptr, nullptr, nullptr, N_INTRON);
  // L1: intron->read, 64->128 (u16 eidx)
  k_layer<64, 128, false, unsigned short><<<gR, 256, 0, stream>>>(
      hI, rp_r, csr_di_r, rs_r, W1, b1, atts, 1, rs_r, hR, nullptr, nullptr, nullptr, N_READ);
  // L2: read->intron, 128->128
  k_layer<128, 128, false, int><<<gI, 256, 0, stream>>>(
      hR, rp_i, csr_si_i, rs_i, W2, b2, atts, 2, rs_i, hI, nullptr, nullptr, nullptr, N_INTRON);
  // L3: intron->read
  k_layer<128, 128, false, unsigned short><<<gR, 256, 0, stream>>>(
      hI, rp_r, csr_di_r, rs_r, W3, b3, atts, 3, rs_r, hR, nullptr, nullptr, nullptr, N_READ);
  // L4: read->intron
  k_layer<128, 128, false, int><<<gI, 256, 0, stream>>>(
      hR, rp_i, csr_si_i, rs_i, W4, b4, atts, 4, rs_i, hI, nullptr, nullptr, nullptr, N_INTRON);
  // L5: intron->read, fc fused in-block (no hR store, no separate fc kernel)
  k_layer<128, 128, true, unsigned short><<<gR, 256, 0, stream>>>(
      hI, rp_r, csr_di_r, rs_r, W5, b5, atts, 5, nullptr, hR, fcw, fcb, out, N_READ);
}